// Round 15
// baseline (816.578 us; speedup 1.0000x reference)
//
#include <hip/hip_runtime.h>
#include <hip/hip_fp16.h>
#include <math.h>

// ---------------------------------------------------------------------------
// GCN 3-layer forward on MI355X.
// Round 15 change: agg was fabric-BW bound (~3.8 TB/s random gathers over a
// 25MB fp16 working set). Aggregation now runs as column-slice passes
// (16 cols = 3.2MB slice, fits a 4MB XCD L2): grid.y = slice, x-fastest
// dispatch keeps ~one slice L2-resident; each src row-slice is reused ~16x
// from L2. epair re-read per slice (sequential, cheap). Same FMA/instr count.
// ---------------------------------------------------------------------------

typedef __bf16 bf16x8 __attribute__((ext_vector_type(8)));
typedef float f32x4 __attribute__((ext_vector_type(4)));

union BF8 {
  unsigned short u[8];
  uint4 q;
  bf16x8 v;
};

union H8 {
  uint4 q;
  __half2 h2[4];
};

__device__ __forceinline__ unsigned short rne_bf16(float f) {
  unsigned u = __float_as_uint(f);
  u += 0x7fff + ((u >> 16) & 1);
  return (unsigned short)(u >> 16);
}
__device__ __forceinline__ float bf16_to_f(unsigned short h) {
  return __uint_as_float((unsigned)h << 16);
}

__device__ __forceinline__ void split_f32_to_bf(const float* av, BF8& ah, BF8& al) {
#pragma unroll
  for (int j = 0; j < 8; ++j) {
    unsigned short hb = rne_bf16(av[j]);
    ah.u[j] = hb;
    al.u[j] = rne_bf16(av[j] - bf16_to_f(hb));
  }
}

// ---- 64-col-slice MFMA gemm body (32KB LDS), 128 rows/block ---------------
__device__ __forceinline__ void gemm_body_slice(const float* __restrict__ A,
    const float* __restrict__ W, int ldw, int col0,
    unsigned short* __restrict__ Ch, int ldc, int M, int bid) {
  constexpr int NF = 4;
  __shared__ __align__(16) unsigned short WT[2][64][128];
  const int t = threadIdx.x;
#pragma unroll
  for (int it = 0; it < 4; ++it) {
    int n = t & 63;
    int kc = it * 4 + (t >> 6);
    int k0 = kc * 8;
    BF8 hh, ll;
#pragma unroll
    for (int j = 0; j < 8; ++j) {
      float w = W[(size_t)(k0 + j) * ldw + col0 + n];
      unsigned short hb = rne_bf16(w);
      hh.u[j] = hb;
      ll.u[j] = rne_bf16(w - bf16_to_f(hb));
    }
    int kk = k0 ^ ((n & 7) << 3);
    *(uint4*)&WT[0][n][kk] = hh.q;
    *(uint4*)&WT[1][n][kk] = ll.q;
  }
  __syncthreads();

  const int wv = t >> 6;
  const int l = t & 63;
  const int lr = l & 15;
  const int lg = l >> 4;
  const int r0 = bid * 128 + wv * 32 + lr;
  const int r1 = r0 + 16;
  const bool v0 = r0 < M, v1 = r1 < M;
  const float* a0p = A + (size_t)r0 * 128;
  const float* a1p = A + (size_t)r1 * 128;

  f32x4 acc0[NF] = {}, acc1[NF] = {};
  float4 p00 = make_float4(0.f, 0.f, 0.f, 0.f), p01 = p00, p10 = p00, p11 = p00;
  if (v0) { p00 = *(const float4*)&a0p[lg * 8]; p01 = *(const float4*)&a0p[lg * 8 + 4]; }
  if (v1) { p10 = *(const float4*)&a1p[lg * 8]; p11 = *(const float4*)&a1p[lg * 8 + 4]; }
#pragma unroll 1
  for (int ks = 0; ks < 4; ++ks) {
    int nkb = ((ks < 3) ? (ks + 1) * 32 : ks * 32) + lg * 8;
    float4 q00 = make_float4(0.f, 0.f, 0.f, 0.f), q01 = q00, q10 = q00, q11 = q00;
    if (v0) { q00 = *(const float4*)&a0p[nkb]; q01 = *(const float4*)&a0p[nkb + 4]; }
    if (v1) { q10 = *(const float4*)&a1p[nkb]; q11 = *(const float4*)&a1p[nkb + 4]; }
    float av0[8] = {p00.x, p00.y, p00.z, p00.w, p01.x, p01.y, p01.z, p01.w};
    float av1[8] = {p10.x, p10.y, p10.z, p10.w, p11.x, p11.y, p11.z, p11.w};
    BF8 ah0, al0, ah1, al1;
    split_f32_to_bf(av0, ah0, al0);
    split_f32_to_bf(av1, ah1, al1);
    int kidx = ks * 32 + lg * 8;
#pragma unroll
    for (int nf = 0; nf < NF; ++nf) {
      int n = nf * 16 + lr;
      int kk = kidx ^ ((n & 7) << 3);
      BF8 bh, bl;
      bh.q = *(const uint4*)&WT[0][n][kk];
      bl.q = *(const uint4*)&WT[1][n][kk];
      acc0[nf] = __builtin_amdgcn_mfma_f32_16x16x32_bf16(ah0.v, bh.v, acc0[nf], 0, 0, 0);
      acc0[nf] = __builtin_amdgcn_mfma_f32_16x16x32_bf16(al0.v, bh.v, acc0[nf], 0, 0, 0);
      acc0[nf] = __builtin_amdgcn_mfma_f32_16x16x32_bf16(ah0.v, bl.v, acc0[nf], 0, 0, 0);
      acc1[nf] = __builtin_amdgcn_mfma_f32_16x16x32_bf16(ah1.v, bh.v, acc1[nf], 0, 0, 0);
      acc1[nf] = __builtin_amdgcn_mfma_f32_16x16x32_bf16(al1.v, bh.v, acc1[nf], 0, 0, 0);
      acc1[nf] = __builtin_amdgcn_mfma_f32_16x16x32_bf16(ah1.v, bl.v, acc1[nf], 0, 0, 0);
    }
    p00 = q00; p01 = q01; p10 = q10; p11 = q11;
  }
  const int ob = bid * 128 + wv * 32 + lg * 4;
#pragma unroll
  for (int j = 0; j < 4; ++j) {
    int orow = ob + j;
    if (orow < M) {
      unsigned short* hr = Ch + (size_t)orow * ldc + col0;
#pragma unroll
      for (int nf = 0; nf < NF; ++nf)
        hr[nf * 16 + lr] = __half_as_ushort(__float2half(acc0[nf][j]));
    }
    int orow1 = ob + 16 + j;
    if (orow1 < M) {
      unsigned short* hr = Ch + (size_t)orow1 * ldc + col0;
#pragma unroll
      for (int nf = 0; nf < NF; ++nf)
        hr[nf * 16 + lr] = __half_as_ushort(__float2half(acc1[nf][j]));
    }
  }
}

// fused dispatch: blocks [0,edgeBlocks) = edge_pass; rest = layer-1 GEMM.
__global__ __launch_bounds__(256) void pre_gemm_fused_kernel(
    const float* __restrict__ x, const float* __restrict__ W1,
    unsigned short* __restrict__ Ch, int M,
    const int* __restrict__ ei, const float* __restrict__ ew,
    unsigned long long* __restrict__ packed, int* __restrict__ rank,
    int E, int edgeBlocks) {
  if ((int)blockIdx.x < edgeBlocks) {
    int e = blockIdx.x * 256 + threadIdx.x;
    if (e >= E) return;
    int d = ei[E + e];
    unsigned wfix = (unsigned)__float2uint_rn(ew[e] * 16777216.0f);  // Q24
    unsigned long long inc = (1ULL << 32) | (unsigned long long)wfix;
    unsigned long long old = atomicAdd(&packed[d], inc);
    rank[e] = (int)(old >> 32);
  } else {
    int g = blockIdx.x - edgeBlocks;
    gemm_body_slice(x, W1, 128, (g & 1) * 64, Ch, 128, M, g >> 1);
  }
}

// ---- LDS-staged full-width MFMA gemm (layers 2,3; fp16 A), 128 rows/block --
template <int NCOL>
__global__ __launch_bounds__(256) void gemm_mfma_kernel(
    const unsigned short* __restrict__ Ah, const float* __restrict__ W,
    unsigned short* __restrict__ Ch, int M) {
  constexpr int NF = NCOL / 16;
  __shared__ __align__(16) unsigned short WT[2][NCOL][128];
  const int t = threadIdx.x;
  constexpr int KC_PER_IT = 256 / NCOL;
#pragma unroll
  for (int it = 0; it < 16 / KC_PER_IT; ++it) {
    int n = t % NCOL;
    int kc = it * KC_PER_IT + t / NCOL;
    int k0 = kc * 8;
    BF8 hh, ll;
#pragma unroll
    for (int j = 0; j < 8; ++j) {
      float w = W[(size_t)(k0 + j) * NCOL + n];
      unsigned short hb = rne_bf16(w);
      hh.u[j] = hb;
      ll.u[j] = rne_bf16(w - bf16_to_f(hb));
    }
    int kk = k0 ^ ((n & 7) << 3);
    *(uint4*)&WT[0][n][kk] = hh.q;
    *(uint4*)&WT[1][n][kk] = ll.q;
  }
  __syncthreads();

  const int wv = t >> 6;
  const int l = t & 63;
  const int lr = l & 15;
  const int lg = l >> 4;
  const int r0 = blockIdx.x * 128 + wv * 32 + lr;
  const int r1 = r0 + 16;
  const bool v0 = r0 < M, v1 = r1 < M;
  const unsigned short* a0p = Ah + (size_t)r0 * 128;
  const unsigned short* a1p = Ah + (size_t)r1 * 128;

  f32x4 acc0[NF] = {}, acc1[NF] = {};
  uint4 ph0 = make_uint4(0, 0, 0, 0), ph1 = ph0;
  if (v0) ph0 = *(const uint4*)&a0p[lg * 8];
  if (v1) ph1 = *(const uint4*)&a1p[lg * 8];
#pragma unroll 1
  for (int ks = 0; ks < 4; ++ks) {
    int nkb = ((ks < 3) ? (ks + 1) * 32 : ks * 32) + lg * 8;
    uint4 qh0 = make_uint4(0, 0, 0, 0), qh1 = qh0;
    if (v0) qh0 = *(const uint4*)&a0p[nkb];
    if (v1) qh1 = *(const uint4*)&a1p[nkb];
    float av0[8], av1[8];
    {
      H8 uu; uu.q = ph0;
#pragma unroll
      for (int j = 0; j < 4; ++j) {
        float2 f = __half22float2(uu.h2[j]);
        av0[j * 2] = f.x; av0[j * 2 + 1] = f.y;
      }
      uu.q = ph1;
#pragma unroll
      for (int j = 0; j < 4; ++j) {
        float2 f = __half22float2(uu.h2[j]);
        av1[j * 2] = f.x; av1[j * 2 + 1] = f.y;
      }
    }
    BF8 ah0, al0, ah1, al1;
    split_f32_to_bf(av0, ah0, al0);
    split_f32_to_bf(av1, ah1, al1);
    int kidx = ks * 32 + lg * 8;
#pragma unroll
    for (int nf = 0; nf < NF; ++nf) {
      int n = nf * 16 + lr;
      int kk = kidx ^ ((n & 7) << 3);
      BF8 bh, bl;
      bh.q = *(const uint4*)&WT[0][n][kk];
      bl.q = *(const uint4*)&WT[1][n][kk];
      acc0[nf] = __builtin_amdgcn_mfma_f32_16x16x32_bf16(ah0.v, bh.v, acc0[nf], 0, 0, 0);
      acc0[nf] = __builtin_amdgcn_mfma_f32_16x16x32_bf16(al0.v, bh.v, acc0[nf], 0, 0, 0);
      acc0[nf] = __builtin_amdgcn_mfma_f32_16x16x32_bf16(ah0.v, bl.v, acc0[nf], 0, 0, 0);
      acc1[nf] = __builtin_amdgcn_mfma_f32_16x16x32_bf16(ah1.v, bh.v, acc1[nf], 0, 0, 0);
      acc1[nf] = __builtin_amdgcn_mfma_f32_16x16x32_bf16(al1.v, bh.v, acc1[nf], 0, 0, 0);
      acc1[nf] = __builtin_amdgcn_mfma_f32_16x16x32_bf16(ah1.v, bl.v, acc1[nf], 0, 0, 0);
    }
    ph0 = qh0; ph1 = qh1;
  }
  const int ob = blockIdx.x * 128 + wv * 32 + lg * 4;
#pragma unroll
  for (int j = 0; j < 4; ++j) {
    int orow = ob + j;
    if (orow < M) {
      unsigned short* hr = Ch + (size_t)orow * NCOL;
#pragma unroll
      for (int nf = 0; nf < NF; ++nf)
        hr[nf * 16 + lr] = __half_as_ushort(__float2half(acc0[nf][j]));
    }
    int orow1 = ob + 16 + j;
    if (orow1 < M) {
      unsigned short* hr = Ch + (size_t)orow1 * NCOL;
#pragma unroll
      for (int nf = 0; nf < NF; ++nf)
        hr[nf * 16 + lr] = __half_as_ushort(__float2half(acc1[nf][j]));
    }
  }
}

// ---- scanA with fused dinv ------------------------------------------------
__global__ __launch_bounds__(1024) void scanA(const unsigned long long* __restrict__ packed,
    int* __restrict__ row_ptr, int* __restrict__ partials,
    float* __restrict__ dinv, int n) {
  __shared__ int sd[1024];
  int t = threadIdx.x;
  int i = blockIdx.x * 1024 + t;
  unsigned long long pv = (i < n) ? packed[i] : 0ULL;
  int v = (int)(pv >> 32);
  if (i < n) {
    float deg = 1.0f + (float)(unsigned)(pv & 0xffffffffULL) * (1.0f / 16777216.0f);
    dinv[i] = 1.0f / sqrtf(deg);
  }
  sd[t] = v;
  __syncthreads();
  for (int off = 1; off < 1024; off <<= 1) {
    int u = (t >= off) ? sd[t - off] : 0;
    __syncthreads();
    sd[t] += u;
    __syncthreads();
  }
  int incl = sd[t];
  if (i < n) row_ptr[i] = incl - v;
  if (t == 1023) partials[blockIdx.x] = incl;
}

__global__ __launch_bounds__(128) void scanB(int* partials, int nb) {
  __shared__ int sd[128];
  int t = threadIdx.x;
  int v = (t < nb) ? partials[t] : 0;
  sd[t] = v;
  __syncthreads();
  for (int off = 1; off < 128; off <<= 1) {
    int u = (t >= off) ? sd[t - off] : 0;
    __syncthreads();
    sd[t] += u;
    __syncthreads();
  }
  int incl = sd[t];
  partials[t] = incl - v;
  if (t == nb - 1) partials[255] = incl;
}

__global__ __launch_bounds__(1024) void scanC(int* row_ptr, const int* __restrict__ partials, int n) {
  int i = blockIdx.x * 1024 + threadIdx.x;
  if (i < n) row_ptr[i] += partials[blockIdx.x];
  if (i == 0) row_ptr[n] = partials[255];
}

__global__ __launch_bounds__(256) void fill_kernel(const int* __restrict__ ei,
    const float* __restrict__ ew, const float* __restrict__ dinv,
    const int* __restrict__ row_ptr, const int* __restrict__ rank,
    int2* __restrict__ epair, int E) {
  int e = blockIdx.x * 256 + threadIdx.x;
  if (e >= E) return;
  int s = ei[e], d = ei[E + e];
  float nw = dinv[s] * ew[e] * dinv[d];
  int p = row_ptr[d] + rank[e];
  epair[p] = make_int2(s, __float_as_int(nw));
}

// ---- sliced aggregation: one 16-col slice per blockIdx.y pass --------------
// out[n, slice] = sum_e norm_e * xw[src_e, slice] + dinv^2*xw[n, slice] + b
// 2 lanes/node x 16B uint4; slice working set 3.2MB -> XCD-L2 resident.
template <int F, bool RELU, bool OUTF16>
__global__ __launch_bounds__(256) void agg_sliced_kernel(
    const unsigned short* __restrict__ xwh,
    const int* __restrict__ row_ptr, const int2* __restrict__ epair,
    const float* __restrict__ dinv, const float* __restrict__ bias,
    void* __restrict__ out, int Nn) {
  constexpr int LPT = F / 8;                  // uint4s per full row
  const int node = blockIdx.x * 128 + (threadIdx.x >> 1);
  const int lane = threadIdx.x & 1;
  const int sl = blockIdx.y;                  // column-slice index
  if (node >= Nn) return;
  const uint4* xh = (const uint4*)xwh;
  const int co = sl * 2 + lane;               // uint4 offset within row
  int start = row_ptr[node];
  int end = row_ptr[node + 1];
  float a0[8] = {}, a1[8] = {};
  int p = start;
  for (; p + 4 <= end; p += 4) {
    int2 e0 = epair[p];
    int2 e1 = epair[p + 1];
    int2 e2 = epair[p + 2];
    int2 e3 = epair[p + 3];
    H8 u0, u1, u2, u3;
    u0.q = xh[(size_t)e0.x * LPT + co];
    u1.q = xh[(size_t)e1.x * LPT + co];
    u2.q = xh[(size_t)e2.x * LPT + co];
    u3.q = xh[(size_t)e3.x * LPT + co];
    float n0 = __int_as_float(e0.y), n1 = __int_as_float(e1.y);
    float n2 = __int_as_float(e2.y), n3 = __int_as_float(e3.y);
#pragma unroll
    for (int j = 0; j < 4; ++j) {
      float2 f0 = __half22float2(u0.h2[j]);
      float2 f1 = __half22float2(u1.h2[j]);
      float2 f2 = __half22float2(u2.h2[j]);
      float2 f3 = __half22float2(u3.h2[j]);
      a0[j * 2]     = fmaf(n0, f0.x, a0[j * 2]);
      a0[j * 2 + 1] = fmaf(n0, f0.y, a0[j * 2 + 1]);
      a1[j * 2]     = fmaf(n1, f1.x, a1[j * 2]);
      a1[j * 2 + 1] = fmaf(n1, f1.y, a1[j * 2 + 1]);
      a0[j * 2]     = fmaf(n2, f2.x, a0[j * 2]);
      a0[j * 2 + 1] = fmaf(n2, f2.y, a0[j * 2 + 1]);
      a1[j * 2]     = fmaf(n3, f3.x, a1[j * 2]);
      a1[j * 2 + 1] = fmaf(n3, f3.y, a1[j * 2 + 1]);
    }
  }
  for (; p < end; ++p) {
    int2 pr = epair[p];
    float nw = __int_as_float(pr.y);
    H8 u; u.q = xh[(size_t)pr.x * LPT + co];
#pragma unroll
    for (int j = 0; j < 4; ++j) {
      float2 f = __half22float2(u.h2[j]);
      a0[j * 2]     = fmaf(nw, f.x, a0[j * 2]);
      a0[j * 2 + 1] = fmaf(nw, f.y, a0[j * 2 + 1]);
    }
  }
  float di = dinv[node];
  float sw = di * di;
  H8 su; su.q = xh[(size_t)node * LPT + co];
#pragma unroll
  for (int j = 0; j < 4; ++j) {
    float2 f = __half22float2(su.h2[j]);
    a0[j * 2]     = fmaf(sw, f.x, a0[j * 2]);
    a0[j * 2 + 1] = fmaf(sw, f.y, a0[j * 2 + 1]);
  }
  float4 b0 = ((const float4*)bias)[co * 2];
  float4 b1 = ((const float4*)bias)[co * 2 + 1];
  float o[8];
  o[0] = a0[0] + a1[0] + b0.x; o[1] = a0[1] + a1[1] + b0.y;
  o[2] = a0[2] + a1[2] + b0.z; o[3] = a0[3] + a1[3] + b0.w;
  o[4] = a0[4] + a1[4] + b1.x; o[5] = a0[5] + a1[5] + b1.y;
  o[6] = a0[6] + a1[6] + b1.z; o[7] = a0[7] + a1[7] + b1.w;
  if (RELU) {
#pragma unroll
    for (int j = 0; j < 8; ++j) o[j] = fmaxf(o[j], 0.f);
  }
  if constexpr (OUTF16) {
    H8 w;
#pragma unroll
    for (int j = 0; j < 4; ++j)
      w.h2[j] = __float22half2_rn(make_float2(o[j * 2], o[j * 2 + 1]));
    ((uint4*)out)[(size_t)node * LPT + co] = w.q;
  } else {
    float4* of = (float4*)out + (size_t)node * (F / 4) + co * 2;
    of[0] = make_float4(o[0], o[1], o[2], o[3]);
    of[1] = make_float4(o[4], o[5], o[6], o[7]);
  }
}

// ---------------------------------------------------------------------------
extern "C" void kernel_launch(void* const* d_in, const int* in_sizes, int n_in,
                              void* d_out, int out_size, void* d_ws, size_t ws_size,
                              hipStream_t stream) {
  const float* x  = (const float*)d_in[0];
  const int*   ei = (const int*)d_in[1];     // int32, [2,E] flat
  const float* ew = (const float*)d_in[2];
  const float* W1 = (const float*)d_in[3];
  const float* b1 = (const float*)d_in[4];
  const float* W2 = (const float*)d_in[5];
  const float* b2 = (const float*)d_in[6];
  const float* W3 = (const float*)d_in[7];
  const float* b3 = (const float*)d_in[8];

  const int N = in_sizes[0] / 128;           // 100000
  const int E = in_sizes[2];                 // 1600000

  // workspace carve (256B aligned)
  char* ws = (char*)d_ws;
  size_t off = 0;
  auto carve = [&](size_t bytes) -> void* {
    void* p = ws + off;
    off += (bytes + 255) & ~(size_t)255;
    return p;
  };
  unsigned long long* packed = (unsigned long long*)carve((size_t)N * 8);
  int*   rank    = (int*)carve((size_t)E * 4);
  float* dinv    = (float*)carve((size_t)N * 4);
  int*   row_ptr = (int*)carve((size_t)(N + 1) * 4);
  int*   parts   = (int*)carve(256 * 4);
  int2*  epair   = (int2*)carve((size_t)E * 8);
  unsigned short* bufH = (unsigned short*)carve((size_t)N * 128 * 2);  // fp16 xw
  unsigned short* bufI = (unsigned short*)carve((size_t)N * 128 * 2);  // fp16 h
  (void)ws_size; (void)n_in; (void)out_size;

  const int nThreads = 256;
  int gE  = (E + nThreads - 1) / nThreads;
  int nb  = (N + 1023) / 1024;               // scan blocks (98)
  const int gMM = (N + 127) / 128;           // 782 MFMA row-blocks (128 rows)
  const int gAggX = (N + 127) / 128;         // 782 node-blocks per slice

  // --- D1: edge_pass (first) co-dispatched with 32KB-LDS layer-1 GEMM ---
  hipMemsetAsync(packed, 0, (size_t)N * 8, stream);
  pre_gemm_fused_kernel<<<gE + 2 * gMM, nThreads, 0, stream>>>(
      x, W1, bufH, N, ei, ew, packed, rank, E, gE);

  // --- graph preprocessing tail (dinv fused into scanA) ---
  scanA<<<nb, 1024, 0, stream>>>(packed, row_ptr, parts, dinv, N);
  scanB<<<1, 128, 0, stream>>>(parts, nb);
  scanC<<<nb, 1024, 0, stream>>>(row_ptr, parts, N);
  fill_kernel<<<gE, nThreads, 0, stream>>>(ei, ew, dinv, row_ptr, rank, epair, E);

  // --- layer 1 aggregate (8 column-slice passes) -> fp16 h1 ---
  agg_sliced_kernel<128, true, true><<<dim3(gAggX, 8), nThreads, 0, stream>>>(
      bufH, row_ptr, epair, dinv, b1, bufI, N);

  // --- layer 2: gemm (fp16 A) -> bufH; agg -> fp16 h2 ---
  gemm_mfma_kernel<128><<<gMM, nThreads, 0, stream>>>(bufI, W2, bufH, N);
  agg_sliced_kernel<128, true, true><<<dim3(gAggX, 8), nThreads, 0, stream>>>(
      bufH, row_ptr, epair, dinv, b2, bufI, N);

  // --- layer 3: gemm 64-wide (fp16 A) -> bufH; agg (4 slices) -> fp32 d_out ---
  gemm_mfma_kernel<64><<<gMM, nThreads, 0, stream>>>(bufI, W3, bufH, N);
  agg_sliced_kernel<64, false, false><<<dim3(gAggX, 4), nThreads, 0, stream>>>(
      bufH, row_ptr, epair, dinv, b3, d_out, N);
}

// Round 16
// 336.226 us; speedup vs baseline: 2.4287x; 2.4287x over previous
//
#include <hip/hip_runtime.h>
#include <hip/hip_fp16.h>
#include <math.h>

// ---------------------------------------------------------------------------
// GCN 3-layer forward on MI355X.
// Round 16: REVERT to round-14 structure (333.8us best). Round-15's column-
// slice agg regressed 2.4x: 32B/edge gathers fetch full 128B lines (4x
// over-fetch, FETCH 902MB) and cross-XCD block spread killed the L2 reuse.
// Full-row 256B gathers fetch exactly the bytes used — traffic-optimal for
// random access. Structure is within ~15-25% of composed floors everywhere:
// fused 105 (atomic ~80 floor), aggs ~155 (fabric ~143), gemm2/3 30 (16),
// scans+fill 40 (25).
// ---------------------------------------------------------------------------

typedef __bf16 bf16x8 __attribute__((ext_vector_type(8)));
typedef float f32x4 __attribute__((ext_vector_type(4)));

union BF8 {
  unsigned short u[8];
  uint4 q;
  bf16x8 v;
};

union H8 {
  uint4 q;
  __half2 h2[4];
};

__device__ __forceinline__ unsigned short rne_bf16(float f) {
  unsigned u = __float_as_uint(f);
  u += 0x7fff + ((u >> 16) & 1);
  return (unsigned short)(u >> 16);
}
__device__ __forceinline__ float bf16_to_f(unsigned short h) {
  return __uint_as_float((unsigned)h << 16);
}

__device__ __forceinline__ void split_f32_to_bf(const float* av, BF8& ah, BF8& al) {
#pragma unroll
  for (int j = 0; j < 8; ++j) {
    unsigned short hb = rne_bf16(av[j]);
    ah.u[j] = hb;
    al.u[j] = rne_bf16(av[j] - bf16_to_f(hb));
  }
}

// ---- 64-col-slice MFMA gemm body (32KB LDS), 128 rows/block ---------------
__device__ __forceinline__ void gemm_body_slice(const float* __restrict__ A,
    const float* __restrict__ W, int ldw, int col0,
    unsigned short* __restrict__ Ch, int ldc, int M, int bid) {
  constexpr int NF = 4;
  __shared__ __align__(16) unsigned short WT[2][64][128];
  const int t = threadIdx.x;
#pragma unroll
  for (int it = 0; it < 4; ++it) {
    int n = t & 63;
    int kc = it * 4 + (t >> 6);
    int k0 = kc * 8;
    BF8 hh, ll;
#pragma unroll
    for (int j = 0; j < 8; ++j) {
      float w = W[(size_t)(k0 + j) * ldw + col0 + n];
      unsigned short hb = rne_bf16(w);
      hh.u[j] = hb;
      ll.u[j] = rne_bf16(w - bf16_to_f(hb));
    }
    int kk = k0 ^ ((n & 7) << 3);
    *(uint4*)&WT[0][n][kk] = hh.q;
    *(uint4*)&WT[1][n][kk] = ll.q;
  }
  __syncthreads();

  const int wv = t >> 6;
  const int l = t & 63;
  const int lr = l & 15;
  const int lg = l >> 4;
  const int r0 = bid * 128 + wv * 32 + lr;
  const int r1 = r0 + 16;
  const bool v0 = r0 < M, v1 = r1 < M;
  const float* a0p = A + (size_t)r0 * 128;
  const float* a1p = A + (size_t)r1 * 128;

  f32x4 acc0[NF] = {}, acc1[NF] = {};
  float4 p00 = make_float4(0.f, 0.f, 0.f, 0.f), p01 = p00, p10 = p00, p11 = p00;
  if (v0) { p00 = *(const float4*)&a0p[lg * 8]; p01 = *(const float4*)&a0p[lg * 8 + 4]; }
  if (v1) { p10 = *(const float4*)&a1p[lg * 8]; p11 = *(const float4*)&a1p[lg * 8 + 4]; }
#pragma unroll 1
  for (int ks = 0; ks < 4; ++ks) {
    int nkb = ((ks < 3) ? (ks + 1) * 32 : ks * 32) + lg * 8;
    float4 q00 = make_float4(0.f, 0.f, 0.f, 0.f), q01 = q00, q10 = q00, q11 = q00;
    if (v0) { q00 = *(const float4*)&a0p[nkb]; q01 = *(const float4*)&a0p[nkb + 4]; }
    if (v1) { q10 = *(const float4*)&a1p[nkb]; q11 = *(const float4*)&a1p[nkb + 4]; }
    float av0[8] = {p00.x, p00.y, p00.z, p00.w, p01.x, p01.y, p01.z, p01.w};
    float av1[8] = {p10.x, p10.y, p10.z, p10.w, p11.x, p11.y, p11.z, p11.w};
    BF8 ah0, al0, ah1, al1;
    split_f32_to_bf(av0, ah0, al0);
    split_f32_to_bf(av1, ah1, al1);
    int kidx = ks * 32 + lg * 8;
#pragma unroll
    for (int nf = 0; nf < NF; ++nf) {
      int n = nf * 16 + lr;
      int kk = kidx ^ ((n & 7) << 3);
      BF8 bh, bl;
      bh.q = *(const uint4*)&WT[0][n][kk];
      bl.q = *(const uint4*)&WT[1][n][kk];
      acc0[nf] = __builtin_amdgcn_mfma_f32_16x16x32_bf16(ah0.v, bh.v, acc0[nf], 0, 0, 0);
      acc0[nf] = __builtin_amdgcn_mfma_f32_16x16x32_bf16(al0.v, bh.v, acc0[nf], 0, 0, 0);
      acc0[nf] = __builtin_amdgcn_mfma_f32_16x16x32_bf16(ah0.v, bl.v, acc0[nf], 0, 0, 0);
      acc1[nf] = __builtin_amdgcn_mfma_f32_16x16x32_bf16(ah1.v, bh.v, acc1[nf], 0, 0, 0);
      acc1[nf] = __builtin_amdgcn_mfma_f32_16x16x32_bf16(al1.v, bh.v, acc1[nf], 0, 0, 0);
      acc1[nf] = __builtin_amdgcn_mfma_f32_16x16x32_bf16(ah1.v, bl.v, acc1[nf], 0, 0, 0);
    }
    p00 = q00; p01 = q01; p10 = q10; p11 = q11;
  }
  const int ob = bid * 128 + wv * 32 + lg * 4;
#pragma unroll
  for (int j = 0; j < 4; ++j) {
    int orow = ob + j;
    if (orow < M) {
      unsigned short* hr = Ch + (size_t)orow * ldc + col0;
#pragma unroll
      for (int nf = 0; nf < NF; ++nf)
        hr[nf * 16 + lr] = __half_as_ushort(__float2half(acc0[nf][j]));
    }
    int orow1 = ob + 16 + j;
    if (orow1 < M) {
      unsigned short* hr = Ch + (size_t)orow1 * ldc + col0;
#pragma unroll
      for (int nf = 0; nf < NF; ++nf)
        hr[nf * 16 + lr] = __half_as_ushort(__float2half(acc1[nf][j]));
    }
  }
}

// fused dispatch: blocks [0,edgeBlocks) = edge_pass; rest = layer-1 GEMM.
__global__ __launch_bounds__(256) void pre_gemm_fused_kernel(
    const float* __restrict__ x, const float* __restrict__ W1,
    unsigned short* __restrict__ Ch, int M,
    const int* __restrict__ ei, const float* __restrict__ ew,
    unsigned long long* __restrict__ packed, int* __restrict__ rank,
    int E, int edgeBlocks) {
  if ((int)blockIdx.x < edgeBlocks) {
    int e = blockIdx.x * 256 + threadIdx.x;
    if (e >= E) return;
    int d = ei[E + e];
    unsigned wfix = (unsigned)__float2uint_rn(ew[e] * 16777216.0f);  // Q24
    unsigned long long inc = (1ULL << 32) | (unsigned long long)wfix;
    unsigned long long old = atomicAdd(&packed[d], inc);
    rank[e] = (int)(old >> 32);
  } else {
    int g = blockIdx.x - edgeBlocks;
    gemm_body_slice(x, W1, 128, (g & 1) * 64, Ch, 128, M, g >> 1);
  }
}

// ---- LDS-staged full-width MFMA gemm (layers 2,3; fp16 A), 128 rows/block --
template <int NCOL>
__global__ __launch_bounds__(256) void gemm_mfma_kernel(
    const unsigned short* __restrict__ Ah, const float* __restrict__ W,
    unsigned short* __restrict__ Ch, int M) {
  constexpr int NF = NCOL / 16;
  __shared__ __align__(16) unsigned short WT[2][NCOL][128];
  const int t = threadIdx.x;
  constexpr int KC_PER_IT = 256 / NCOL;
#pragma unroll
  for (int it = 0; it < 16 / KC_PER_IT; ++it) {
    int n = t % NCOL;
    int kc = it * KC_PER_IT + t / NCOL;
    int k0 = kc * 8;
    BF8 hh, ll;
#pragma unroll
    for (int j = 0; j < 8; ++j) {
      float w = W[(size_t)(k0 + j) * NCOL + n];
      unsigned short hb = rne_bf16(w);
      hh.u[j] = hb;
      ll.u[j] = rne_bf16(w - bf16_to_f(hb));
    }
    int kk = k0 ^ ((n & 7) << 3);
    *(uint4*)&WT[0][n][kk] = hh.q;
    *(uint4*)&WT[1][n][kk] = ll.q;
  }
  __syncthreads();

  const int wv = t >> 6;
  const int l = t & 63;
  const int lr = l & 15;
  const int lg = l >> 4;
  const int r0 = blockIdx.x * 128 + wv * 32 + lr;
  const int r1 = r0 + 16;
  const bool v0 = r0 < M, v1 = r1 < M;
  const unsigned short* a0p = Ah + (size_t)r0 * 128;
  const unsigned short* a1p = Ah + (size_t)r1 * 128;

  f32x4 acc0[NF] = {}, acc1[NF] = {};
  uint4 ph0 = make_uint4(0, 0, 0, 0), ph1 = ph0;
  if (v0) ph0 = *(const uint4*)&a0p[lg * 8];
  if (v1) ph1 = *(const uint4*)&a1p[lg * 8];
#pragma unroll 1
  for (int ks = 0; ks < 4; ++ks) {
    int nkb = ((ks < 3) ? (ks + 1) * 32 : ks * 32) + lg * 8;
    uint4 qh0 = make_uint4(0, 0, 0, 0), qh1 = qh0;
    if (v0) qh0 = *(const uint4*)&a0p[nkb];
    if (v1) qh1 = *(const uint4*)&a1p[nkb];
    float av0[8], av1[8];
    {
      H8 uu; uu.q = ph0;
#pragma unroll
      for (int j = 0; j < 4; ++j) {
        float2 f = __half22float2(uu.h2[j]);
        av0[j * 2] = f.x; av0[j * 2 + 1] = f.y;
      }
      uu.q = ph1;
#pragma unroll
      for (int j = 0; j < 4; ++j) {
        float2 f = __half22float2(uu.h2[j]);
        av1[j * 2] = f.x; av1[j * 2 + 1] = f.y;
      }
    }
    BF8 ah0, al0, ah1, al1;
    split_f32_to_bf(av0, ah0, al0);
    split_f32_to_bf(av1, ah1, al1);
    int kidx = ks * 32 + lg * 8;
#pragma unroll
    for (int nf = 0; nf < NF; ++nf) {
      int n = nf * 16 + lr;
      int kk = kidx ^ ((n & 7) << 3);
      BF8 bh, bl;
      bh.q = *(const uint4*)&WT[0][n][kk];
      bl.q = *(const uint4*)&WT[1][n][kk];
      acc0[nf] = __builtin_amdgcn_mfma_f32_16x16x32_bf16(ah0.v, bh.v, acc0[nf], 0, 0, 0);
      acc0[nf] = __builtin_amdgcn_mfma_f32_16x16x32_bf16(al0.v, bh.v, acc0[nf], 0, 0, 0);
      acc0[nf] = __builtin_amdgcn_mfma_f32_16x16x32_bf16(ah0.v, bl.v, acc0[nf], 0, 0, 0);
      acc1[nf] = __builtin_amdgcn_mfma_f32_16x16x32_bf16(ah1.v, bh.v, acc1[nf], 0, 0, 0);
      acc1[nf] = __builtin_amdgcn_mfma_f32_16x16x32_bf16(al1.v, bh.v, acc1[nf], 0, 0, 0);
      acc1[nf] = __builtin_amdgcn_mfma_f32_16x16x32_bf16(ah1.v, bl.v, acc1[nf], 0, 0, 0);
    }
    ph0 = qh0; ph1 = qh1;
  }
  const int ob = blockIdx.x * 128 + wv * 32 + lg * 4;
#pragma unroll
  for (int j = 0; j < 4; ++j) {
    int orow = ob + j;
    if (orow < M) {
      unsigned short* hr = Ch + (size_t)orow * NCOL;
#pragma unroll
      for (int nf = 0; nf < NF; ++nf)
        hr[nf * 16 + lr] = __half_as_ushort(__float2half(acc0[nf][j]));
    }
    int orow1 = ob + 16 + j;
    if (orow1 < M) {
      unsigned short* hr = Ch + (size_t)orow1 * NCOL;
#pragma unroll
      for (int nf = 0; nf < NF; ++nf)
        hr[nf * 16 + lr] = __half_as_ushort(__float2half(acc1[nf][j]));
    }
  }
}

// ---- scanA with fused dinv ------------------------------------------------
__global__ __launch_bounds__(1024) void scanA(const unsigned long long* __restrict__ packed,
    int* __restrict__ row_ptr, int* __restrict__ partials,
    float* __restrict__ dinv, int n) {
  __shared__ int sd[1024];
  int t = threadIdx.x;
  int i = blockIdx.x * 1024 + t;
  unsigned long long pv = (i < n) ? packed[i] : 0ULL;
  int v = (int)(pv >> 32);
  if (i < n) {
    float deg = 1.0f + (float)(unsigned)(pv & 0xffffffffULL) * (1.0f / 16777216.0f);
    dinv[i] = 1.0f / sqrtf(deg);
  }
  sd[t] = v;
  __syncthreads();
  for (int off = 1; off < 1024; off <<= 1) {
    int u = (t >= off) ? sd[t - off] : 0;
    __syncthreads();
    sd[t] += u;
    __syncthreads();
  }
  int incl = sd[t];
  if (i < n) row_ptr[i] = incl - v;
  if (t == 1023) partials[blockIdx.x] = incl;
}

__global__ __launch_bounds__(128) void scanB(int* partials, int nb) {
  __shared__ int sd[128];
  int t = threadIdx.x;
  int v = (t < nb) ? partials[t] : 0;
  sd[t] = v;
  __syncthreads();
  for (int off = 1; off < 128; off <<= 1) {
    int u = (t >= off) ? sd[t - off] : 0;
    __syncthreads();
    sd[t] += u;
    __syncthreads();
  }
  int incl = sd[t];
  partials[t] = incl - v;
  if (t == nb - 1) partials[255] = incl;
}

__global__ __launch_bounds__(1024) void scanC(int* row_ptr, const int* __restrict__ partials, int n) {
  int i = blockIdx.x * 1024 + threadIdx.x;
  if (i < n) row_ptr[i] += partials[blockIdx.x];
  if (i == 0) row_ptr[n] = partials[255];
}

__global__ __launch_bounds__(256) void fill_kernel(const int* __restrict__ ei,
    const float* __restrict__ ew, const float* __restrict__ dinv,
    const int* __restrict__ row_ptr, const int* __restrict__ rank,
    int2* __restrict__ epair, int E) {
  int e = blockIdx.x * 256 + threadIdx.x;
  if (e >= E) return;
  int s = ei[e], d = ei[E + e];
  float nw = dinv[s] * ew[e] * dinv[d];
  int p = row_ptr[d] + rank[e];
  epair[p] = make_int2(s, __float_as_int(nw));
}

// ---- aggregation: out[n] = sum_{e: dst=n} norm_e * xw[src_e] + dinv^2*xw[n] + b
// 16B uint4 gathers (8 halves/lane), F/8 lanes per node, x4 edge unroll.
template <int F, bool RELU, bool OUTF16>
__global__ __launch_bounds__(256) void agg_kernel(const unsigned short* __restrict__ xwh,
    const int* __restrict__ row_ptr, const int2* __restrict__ epair,
    const float* __restrict__ dinv, const float* __restrict__ bias,
    void* __restrict__ out, int Nn) {
  constexpr int LPN = F / 8;                  // lanes per node (8 dims each)
  int t = blockIdx.x * 256 + threadIdx.x;
  int node = t / LPN;
  int lane = t % LPN;
  if (node >= Nn) return;
  const uint4* xh = (const uint4*)xwh;        // 8 halves per uint4
  int start = row_ptr[node];
  int end = row_ptr[node + 1];
  float a0[8] = {}, a1[8] = {};               // two fma chains
  int p = start;
  for (; p + 4 <= end; p += 4) {
    int2 e0 = epair[p];
    int2 e1 = epair[p + 1];
    int2 e2 = epair[p + 2];
    int2 e3 = epair[p + 3];
    H8 u0, u1, u2, u3;
    u0.q = xh[(size_t)e0.x * LPN + lane];
    u1.q = xh[(size_t)e1.x * LPN + lane];
    u2.q = xh[(size_t)e2.x * LPN + lane];
    u3.q = xh[(size_t)e3.x * LPN + lane];
    float n0 = __int_as_float(e0.y), n1 = __int_as_float(e1.y);
    float n2 = __int_as_float(e2.y), n3 = __int_as_float(e3.y);
#pragma unroll
    for (int j = 0; j < 4; ++j) {
      float2 f0 = __half22float2(u0.h2[j]);
      float2 f1 = __half22float2(u1.h2[j]);
      float2 f2 = __half22float2(u2.h2[j]);
      float2 f3 = __half22float2(u3.h2[j]);
      a0[j * 2]     = fmaf(n0, f0.x, a0[j * 2]);
      a0[j * 2 + 1] = fmaf(n0, f0.y, a0[j * 2 + 1]);
      a1[j * 2]     = fmaf(n1, f1.x, a1[j * 2]);
      a1[j * 2 + 1] = fmaf(n1, f1.y, a1[j * 2 + 1]);
      a0[j * 2]     = fmaf(n2, f2.x, a0[j * 2]);
      a0[j * 2 + 1] = fmaf(n2, f2.y, a0[j * 2 + 1]);
      a1[j * 2]     = fmaf(n3, f3.x, a1[j * 2]);
      a1[j * 2 + 1] = fmaf(n3, f3.y, a1[j * 2 + 1]);
    }
  }
  for (; p < end; ++p) {
    int2 pr = epair[p];
    float nw = __int_as_float(pr.y);
    H8 u; u.q = xh[(size_t)pr.x * LPN + lane];
#pragma unroll
    for (int j = 0; j < 4; ++j) {
      float2 f = __half22float2(u.h2[j]);
      a0[j * 2]     = fmaf(nw, f.x, a0[j * 2]);
      a0[j * 2 + 1] = fmaf(nw, f.y, a0[j * 2 + 1]);
    }
  }
  float di = dinv[node];
  float sw = di * di;
  H8 su; su.q = xh[(size_t)node * LPN + lane];
#pragma unroll
  for (int j = 0; j < 4; ++j) {
    float2 f = __half22float2(su.h2[j]);
    a0[j * 2]     = fmaf(sw, f.x, a0[j * 2]);
    a0[j * 2 + 1] = fmaf(sw, f.y, a0[j * 2 + 1]);
  }
  float4 b0 = ((const float4*)bias)[lane * 2];
  float4 b1 = ((const float4*)bias)[lane * 2 + 1];
  float o[8];
  o[0] = a0[0] + a1[0] + b0.x; o[1] = a0[1] + a1[1] + b0.y;
  o[2] = a0[2] + a1[2] + b0.z; o[3] = a0[3] + a1[3] + b0.w;
  o[4] = a0[4] + a1[4] + b1.x; o[5] = a0[5] + a1[5] + b1.y;
  o[6] = a0[6] + a1[6] + b1.z; o[7] = a0[7] + a1[7] + b1.w;
  if (RELU) {
#pragma unroll
    for (int j = 0; j < 8; ++j) o[j] = fmaxf(o[j], 0.f);
  }
  if constexpr (OUTF16) {
    H8 w;
#pragma unroll
    for (int j = 0; j < 4; ++j)
      w.h2[j] = __float22half2_rn(make_float2(o[j * 2], o[j * 2 + 1]));
    ((uint4*)out)[(size_t)node * LPN + lane] = w.q;
  } else {
    float4* of = (float4*)out + (size_t)node * LPN * 2 + lane * 2;
    of[0] = make_float4(o[0], o[1], o[2], o[3]);
    of[1] = make_float4(o[4], o[5], o[6], o[7]);
  }
}

// ---------------------------------------------------------------------------
extern "C" void kernel_launch(void* const* d_in, const int* in_sizes, int n_in,
                              void* d_out, int out_size, void* d_ws, size_t ws_size,
                              hipStream_t stream) {
  const float* x  = (const float*)d_in[0];
  const int*   ei = (const int*)d_in[1];     // int32, [2,E] flat
  const float* ew = (const float*)d_in[2];
  const float* W1 = (const float*)d_in[3];
  const float* b1 = (const float*)d_in[4];
  const float* W2 = (const float*)d_in[5];
  const float* b2 = (const float*)d_in[6];
  const float* W3 = (const float*)d_in[7];
  const float* b3 = (const float*)d_in[8];

  const int N = in_sizes[0] / 128;           // 100000
  const int E = in_sizes[2];                 // 1600000

  // workspace carve (256B aligned)
  char* ws = (char*)d_ws;
  size_t off = 0;
  auto carve = [&](size_t bytes) -> void* {
    void* p = ws + off;
    off += (bytes + 255) & ~(size_t)255;
    return p;
  };
  unsigned long long* packed = (unsigned long long*)carve((size_t)N * 8);
  int*   rank    = (int*)carve((size_t)E * 4);
  float* dinv    = (float*)carve((size_t)N * 4);
  int*   row_ptr = (int*)carve((size_t)(N + 1) * 4);
  int*   parts   = (int*)carve(256 * 4);
  int2*  epair   = (int2*)carve((size_t)E * 8);
  unsigned short* bufH = (unsigned short*)carve((size_t)N * 128 * 2);  // fp16 xw
  unsigned short* bufI = (unsigned short*)carve((size_t)N * 128 * 2);  // fp16 h
  (void)ws_size; (void)n_in; (void)out_size;

  const int nThreads = 256;
  int gE  = (E + nThreads - 1) / nThreads;
  int nb  = (N + 1023) / 1024;               // scan blocks (98)
  const int gMM = (N + 127) / 128;           // 782 MFMA row-blocks (128 rows)
  int gAgg128 = (N * 16 + nThreads - 1) / nThreads;
  int gAgg64  = (N * 8 + nThreads - 1) / nThreads;

  // --- D1: edge_pass (first) co-dispatched with 32KB-LDS layer-1 GEMM ---
  hipMemsetAsync(packed, 0, (size_t)N * 8, stream);
  pre_gemm_fused_kernel<<<gE + 2 * gMM, nThreads, 0, stream>>>(
      x, W1, bufH, N, ei, ew, packed, rank, E, gE);

  // --- graph preprocessing tail (dinv fused into scanA) ---
  scanA<<<nb, 1024, 0, stream>>>(packed, row_ptr, parts, dinv, N);
  scanB<<<1, 128, 0, stream>>>(parts, nb);
  scanC<<<nb, 1024, 0, stream>>>(row_ptr, parts, N);
  fill_kernel<<<gE, nThreads, 0, stream>>>(ei, ew, dinv, row_ptr, rank, epair, E);

  // --- layer 1 aggregate -> fp16 h1 ---
  agg_kernel<128, true, true><<<gAgg128, nThreads, 0, stream>>>(bufH, row_ptr, epair, dinv, b1, bufI, N);

  // --- layer 2: gemm (fp16 A) -> bufH; agg -> fp16 h2 ---
  gemm_mfma_kernel<128><<<gMM, nThreads, 0, stream>>>(bufI, W2, bufH, N);
  agg_kernel<128, true, true><<<gAgg128, nThreads, 0, stream>>>(bufH, row_ptr, epair, dinv, b2, bufI, N);

  // --- layer 3: gemm 64-wide (fp16 A) -> bufH; agg -> fp32 d_out ---
  gemm_mfma_kernel<64><<<gMM, nThreads, 0, stream>>>(bufI, W3, bufH, N);
  agg_kernel<64, false, false><<<gAgg64, nThreads, 0, stream>>>(bufH, row_ptr, epair, dinv, b3, d_out, N);
}